// Round 4
// baseline (298.393 us; speedup 1.0000x reference)
//
#include <hip/hip_runtime.h>
#include <hip/hip_bf16.h>
#include <hip/hip_cooperative_groups.h>

namespace cg = cooperative_groups;

#define N_NODES 8192
#define F_IN    512
#define H_DIM   256
#define O_DIM   128
#define C_DIM   64
#define E_EDGES 262144

typedef __attribute__((ext_vector_type(8))) short bf16x8;
typedef __attribute__((ext_vector_type(4))) float f32x4;

__device__ inline unsigned short f2bf(float v) {
    __hip_bfloat16 h = __float2bfloat16(v);
    return *reinterpret_cast<unsigned short*>(&h);
}
__device__ inline float bf2f(unsigned short u) {
    return __uint_as_float((unsigned)u << 16);
}
__device__ inline void split2(float v, unsigned short& hi, unsigned short& lo) {
    hi = f2bf(v);
    lo = f2bf(v - bf2f(hi));
}
__device__ inline float4 bf4_to_f4(ushort4 u) {
    float4 f;
    f.x = bf2f(u.x); f.y = bf2f(u.y); f.z = bf2f(u.z); f.w = bf2f(u.w);
    return f;
}

// ---------------- cooperative CSR build: zero -> hist -> scan(+dinv) -> fill ----------------
__global__ __launch_bounds__(256) void csr_build_kernel(
    const int* __restrict__ srcv, const int* __restrict__ dstv,
    int* __restrict__ cnt, int* __restrict__ row_ptr,
    int* __restrict__ cursor, int* __restrict__ csr_src,
    float* __restrict__ dinv)
{
    cg::grid_group grid = cg::this_grid();
    const int tid = blockIdx.x * 256 + threadIdx.x;
    const int nthr = gridDim.x * 256;

    // phase 1: zero counts
    for (int i = tid; i < N_NODES; i += nthr) cnt[i] = 0;
    grid.sync();

    // phase 2: histogram of dst
    for (int e = tid; e < E_EDGES; e += nthr) atomicAdd(&cnt[dstv[e]], 1);
    grid.sync();

    // phase 3: exclusive scan (block 0), cursor init, dinv
    if (blockIdx.x == 0) {
        __shared__ int partial[256];
        const int t = threadIdx.x;
        const int base = t * 32;
        int cl[32];
        int s = 0;
#pragma unroll
        for (int j = 0; j < 32; ++j) { cl[j] = cnt[base + j]; s += cl[j]; }
        partial[t] = s;
        __syncthreads();
        for (int off = 1; off < 256; off <<= 1) {
            int v = (t >= off) ? partial[t - off] : 0;
            __syncthreads();
            if (t >= off) partial[t] += v;
            __syncthreads();
        }
        int ex = (t == 0) ? 0 : partial[t - 1];
#pragma unroll
        for (int j = 0; j < 32; ++j) {
            row_ptr[base + j] = ex;
            cursor[base + j] = ex;
            ex += cl[j];
            dinv[base + j] = rsqrtf((float)cl[j] + 1.0f);
        }
        if (t == 255) row_ptr[N_NODES] = ex;
    }
    grid.sync();

    // phase 4: bucket fill
    for (int e = tid; e < E_EDGES; e += nthr) {
        int d = dstv[e];
        int pos = atomicAdd(&cursor[d], 1);
        csr_src[pos] = srcv[e];
    }
}

// ---------------- fused split: x -> xh/xl ; W1 -> W1^T hi/lo ; W2 -> W2^T hi/lo ----------------
__global__ __launch_bounds__(256) void split_all_kernel(
    const float* __restrict__ x, unsigned short* __restrict__ xh, unsigned short* __restrict__ xl,
    const float* __restrict__ W1, unsigned short* __restrict__ w1th, unsigned short* __restrict__ w1tl,
    const float* __restrict__ W2, unsigned short* __restrict__ w2th, unsigned short* __restrict__ w2tl)
{
    const int NX4 = N_NODES * F_IN / 4;       // 1048576 float4 of x
    const int NW1 = F_IN * H_DIM;             // 131072
    const int NW2 = H_DIM * O_DIM;            // 32768
    int idx = blockIdx.x * 256 + threadIdx.x;
    if (idx < NX4) {
        float4 v = ((const float4*)x)[idx];
        ushort4 h, l;
        split2(v.x, h.x, l.x);
        split2(v.y, h.y, l.y);
        split2(v.z, h.z, l.z);
        split2(v.w, h.w, l.w);
        ((ushort4*)xh)[idx] = h;
        ((ushort4*)xl)[idx] = l;
    } else if (idx < NX4 + NW1) {
        int j = idx - NX4;
        int k = j / H_DIM, n = j % H_DIM;
        unsigned short h, l;
        split2(W1[j], h, l);
        w1th[n * F_IN + k] = h;
        w1tl[n * F_IN + k] = l;
    } else if (idx < NX4 + NW1 + NW2) {
        int j = idx - NX4 - NW1;
        int k = j / O_DIM, n = j % O_DIM;
        unsigned short h, l;
        split2(W2[j], h, l);
        w2th[n * H_DIM + k] = h;
        w2tl[n * H_DIM + k] = l;
    }
}

// ---------------- split-bf16 MFMA GEMM: out = dinv ⊙ (A @ Bt^T), bf16 output ----------------
// A: [M x K] bf16 hi/lo, Bt: [N x K] bf16 hi/lo. 4 waves as 2x2; wave tile (MW*16) x (NW*16).
template<int N, int K, int MW, int NW>
__global__ __launch_bounds__(256) void gemm_mfma_kernel(
    const unsigned short* __restrict__ Ah, const unsigned short* __restrict__ Al,
    const unsigned short* __restrict__ Bth, const unsigned short* __restrict__ Btl,
    const float* __restrict__ dinv, unsigned short* __restrict__ out)
{
    const int tid = threadIdx.x;
    const int lane = tid & 63;
    const int wid = tid >> 6;
    const int r = lane & 15;
    const int kg = lane >> 4;
    const int m0 = blockIdx.y * (2 * MW * 16) + (wid >> 1) * (MW * 16);
    const int n0 = blockIdx.x * (2 * NW * 16) + (wid & 1) * (NW * 16);

    f32x4 acc[MW][NW];
#pragma unroll
    for (int mi = 0; mi < MW; ++mi)
#pragma unroll
        for (int ni = 0; ni < NW; ++ni) acc[mi][ni] = (f32x4){0.f, 0.f, 0.f, 0.f};

    for (int k0 = 0; k0 < K; k0 += 32) {
        const int kof = k0 + kg * 8;
        bf16x8 ah[MW], al[MW], bh[NW], bl[NW];
#pragma unroll
        for (int mi = 0; mi < MW; ++mi) {
            size_t off = (size_t)(m0 + mi * 16 + r) * K + kof;
            ah[mi] = *(const bf16x8*)(Ah + off);
            al[mi] = *(const bf16x8*)(Al + off);
        }
#pragma unroll
        for (int ni = 0; ni < NW; ++ni) {
            size_t off = (size_t)(n0 + ni * 16 + r) * K + kof;
            bh[ni] = *(const bf16x8*)(Bth + off);
            bl[ni] = *(const bf16x8*)(Btl + off);
        }
#pragma unroll
        for (int mi = 0; mi < MW; ++mi)
#pragma unroll
            for (int ni = 0; ni < NW; ++ni) {
                acc[mi][ni] = __builtin_amdgcn_mfma_f32_16x16x32_bf16(ah[mi], bh[ni], acc[mi][ni], 0, 0, 0);
                acc[mi][ni] = __builtin_amdgcn_mfma_f32_16x16x32_bf16(ah[mi], bl[ni], acc[mi][ni], 0, 0, 0);
                acc[mi][ni] = __builtin_amdgcn_mfma_f32_16x16x32_bf16(al[mi], bh[ni], acc[mi][ni], 0, 0, 0);
            }
    }

#pragma unroll
    for (int mi = 0; mi < MW; ++mi) {
        int rowb = m0 + mi * 16 + kg * 4;
        float di[4];
#pragma unroll
        for (int i = 0; i < 4; ++i) di[i] = dinv[rowb + i];
#pragma unroll
        for (int ni = 0; ni < NW; ++ni) {
            int col = n0 + ni * 16 + r;
#pragma unroll
            for (int i = 0; i < 4; ++i)
                out[(size_t)(rowb + i) * N + col] = f2bf(di[i] * acc[mi][ni][i]);
        }
    }
}

// ---------------- gather layer 1 (bf16 g1): h = relu(dinv*(sum+self)+b), write hi/lo split ----------------
__global__ __launch_bounds__(256) void gather1_kernel(
    const unsigned short* __restrict__ g,   // [N_NODES][256] bf16
    const int* __restrict__ row_ptr, const int* __restrict__ csr_src,
    const float* __restrict__ dinv, const float* __restrict__ b,
    unsigned short* __restrict__ hh, unsigned short* __restrict__ hl)
{
    const int wid = threadIdx.x >> 6;
    const int lane = threadIdx.x & 63;
    const int node = blockIdx.x * 4 + wid;
    if (node >= N_NODES) return;

    const ushort4* G4 = (const ushort4*)g;  // row stride 64 ushort4
    const int beg = row_ptr[node];
    const int end = row_ptr[node + 1];

    float4 acc = bf4_to_f4(G4[(size_t)node * 64 + lane]);  // self
    float4 acc2 = make_float4(0.f, 0.f, 0.f, 0.f);

    int e = beg;
    for (; e + 4 <= end; e += 4) {
        int s0 = csr_src[e], s1 = csr_src[e + 1], s2 = csr_src[e + 2], s3 = csr_src[e + 3];
        float4 v0 = bf4_to_f4(G4[(size_t)s0 * 64 + lane]);
        float4 v1 = bf4_to_f4(G4[(size_t)s1 * 64 + lane]);
        float4 v2 = bf4_to_f4(G4[(size_t)s2 * 64 + lane]);
        float4 v3 = bf4_to_f4(G4[(size_t)s3 * 64 + lane]);
        acc.x += v0.x + v1.x; acc.y += v0.y + v1.y;
        acc.z += v0.z + v1.z; acc.w += v0.w + v1.w;
        acc2.x += v2.x + v3.x; acc2.y += v2.y + v3.y;
        acc2.z += v2.z + v3.z; acc2.w += v2.w + v3.w;
    }
    for (; e < end; ++e) {
        float4 v0 = bf4_to_f4(G4[(size_t)csr_src[e] * 64 + lane]);
        acc.x += v0.x; acc.y += v0.y; acc.z += v0.z; acc.w += v0.w;
    }
    acc.x += acc2.x; acc.y += acc2.y; acc.z += acc2.z; acc.w += acc2.w;

    float di = dinv[node];
    const float4 bv = ((const float4*)b)[lane];
    float4 rr;
    rr.x = di * acc.x + bv.x;
    rr.y = di * acc.y + bv.y;
    rr.z = di * acc.z + bv.z;
    rr.w = di * acc.w + bv.w;
    rr.x = rr.x > 0.f ? rr.x : 0.f;
    rr.y = rr.y > 0.f ? rr.y : 0.f;
    rr.z = rr.z > 0.f ? rr.z : 0.f;
    rr.w = rr.w > 0.f ? rr.w : 0.f;

    ushort4 h, l;
    split2(rr.x, h.x, l.x);
    split2(rr.y, h.y, l.y);
    split2(rr.z, h.z, l.z);
    split2(rr.w, h.w, l.w);
    ((ushort4*)hh)[(size_t)node * 64 + lane] = h;
    ((ushort4*)hl)[(size_t)node * 64 + lane] = l;
}

// ---------------- fused gather layer 2 + head: z -> mu, logvar, zr(hi/lo) ----------------
// one block (128 threads) per node; thread t owns feature t of z.
__global__ __launch_bounds__(128) void gather_head_kernel(
    const unsigned short* __restrict__ g2,  // [N_NODES][128] bf16
    const int* __restrict__ row_ptr, const int* __restrict__ csr_src,
    const float* __restrict__ dinv, const float* __restrict__ b2,
    const float* __restrict__ Wmu, const float* __restrict__ bmu,
    const float* __restrict__ Wlv, const float* __restrict__ blv,
    const float* __restrict__ eps,
    float* __restrict__ mu_out, float* __restrict__ lv_out,
    unsigned short* __restrict__ zrh, unsigned short* __restrict__ zrl)
{
    __shared__ float zs[O_DIM];
    __shared__ float mu_s[C_DIM];
    __shared__ float lv_s[C_DIM];
    const int node = blockIdx.x;
    const int t = threadIdx.x;

    const int beg = row_ptr[node];
    const int end = row_ptr[node + 1];

    float acc = bf2f(g2[(size_t)node * O_DIM + t]);  // self
    float acc2 = 0.f;
    int e = beg;
    for (; e + 4 <= end; e += 4) {
        int s0 = csr_src[e], s1 = csr_src[e + 1], s2 = csr_src[e + 2], s3 = csr_src[e + 3];
        acc  += bf2f(g2[(size_t)s0 * O_DIM + t]) + bf2f(g2[(size_t)s1 * O_DIM + t]);
        acc2 += bf2f(g2[(size_t)s2 * O_DIM + t]) + bf2f(g2[(size_t)s3 * O_DIM + t]);
    }
    for (; e < end; ++e) acc += bf2f(g2[(size_t)csr_src[e] * O_DIM + t]);
    acc += acc2;

    zs[t] = dinv[node] * acc + b2[t];
    __syncthreads();

    const int c = t & 63;
    const float* W = (t < 64) ? Wmu : Wlv;
    float s = 0.f;
#pragma unroll 8
    for (int k = 0; k < O_DIM; ++k) s += zs[k] * W[k * C_DIM + c];
    if (t < 64) {
        s += bmu[c];
        mu_out[(size_t)node * C_DIM + c] = s;
        mu_s[c] = s;
    } else {
        s += blv[c];
        lv_out[(size_t)node * C_DIM + c] = s;
        lv_s[c] = s;
    }
    __syncthreads();
    if (t < 64) {
        float stdv = __expf(0.5f * lv_s[c]);
        float v = mu_s[c] + eps[(size_t)node * C_DIM + c] * stdv;
        unsigned short h, l;
        split2(v, h, l);
        zrh[(size_t)node * C_DIM + c] = h;
        zrl[(size_t)node * C_DIM + c] = l;
    }
}

// ---------------- adj = sigmoid(zr @ zr^T) via split-bf16 MFMA ----------------
__global__ __launch_bounds__(256) void adj_mfma_kernel(
    const unsigned short* __restrict__ Zh, const unsigned short* __restrict__ Zl,
    float* __restrict__ out)
{
    const int tid = threadIdx.x;
    const int lane = tid & 63;
    const int wid = tid >> 6;
    const int r = lane & 15;
    const int kg = lane >> 4;
    const int m0 = blockIdx.y * 128 + (wid >> 1) * 64;
    const int n0 = blockIdx.x * 128 + (wid & 1) * 64;

    bf16x8 ah[4][2], al[4][2];
#pragma unroll
    for (int mi = 0; mi < 4; ++mi)
#pragma unroll
        for (int ks = 0; ks < 2; ++ks) {
            size_t off = (size_t)(m0 + mi * 16 + r) * C_DIM + ks * 32 + kg * 8;
            ah[mi][ks] = *(const bf16x8*)(Zh + off);
            al[mi][ks] = *(const bf16x8*)(Zl + off);
        }

    f32x4 acc[4][4];
#pragma unroll
    for (int mi = 0; mi < 4; ++mi)
#pragma unroll
        for (int ni = 0; ni < 4; ++ni) acc[mi][ni] = (f32x4){0.f, 0.f, 0.f, 0.f};

#pragma unroll
    for (int ni = 0; ni < 4; ++ni) {
        bf16x8 bh[2], bl[2];
#pragma unroll
        for (int ks = 0; ks < 2; ++ks) {
            size_t off = (size_t)(n0 + ni * 16 + r) * C_DIM + ks * 32 + kg * 8;
            bh[ks] = *(const bf16x8*)(Zh + off);
            bl[ks] = *(const bf16x8*)(Zl + off);
        }
#pragma unroll
        for (int mi = 0; mi < 4; ++mi)
#pragma unroll
            for (int ks = 0; ks < 2; ++ks) {
                acc[mi][ni] = __builtin_amdgcn_mfma_f32_16x16x32_bf16(ah[mi][ks], bh[ks], acc[mi][ni], 0, 0, 0);
                acc[mi][ni] = __builtin_amdgcn_mfma_f32_16x16x32_bf16(ah[mi][ks], bl[ks], acc[mi][ni], 0, 0, 0);
                acc[mi][ni] = __builtin_amdgcn_mfma_f32_16x16x32_bf16(al[mi][ks], bh[ks], acc[mi][ni], 0, 0, 0);
            }
    }

#pragma unroll
    for (int mi = 0; mi < 4; ++mi) {
        int rowb = m0 + mi * 16 + kg * 4;
#pragma unroll
        for (int ni = 0; ni < 4; ++ni) {
            int col = n0 + ni * 16 + r;
#pragma unroll
            for (int i = 0; i < 4; ++i) {
                float v = acc[mi][ni][i];
                float e = __expf(-v);
                out[(size_t)(rowb + i) * N_NODES + col] = __builtin_amdgcn_rcpf(1.0f + e);
            }
        }
    }
}

extern "C" void kernel_launch(void* const* d_in, const int* in_sizes, int n_in,
                              void* d_out, int out_size, void* d_ws, size_t ws_size,
                              hipStream_t stream) {
    const float* x   = (const float*)d_in[0];
    const int*   ei  = (const int*)  d_in[1];
    const float* eps = (const float*)d_in[2];
    const float* W1  = (const float*)d_in[3];
    const float* b1  = (const float*)d_in[4];
    const float* W2  = (const float*)d_in[5];
    const float* b2  = (const float*)d_in[6];
    const float* Wmu = (const float*)d_in[7];
    const float* bmu = (const float*)d_in[8];
    const float* Wlv = (const float*)d_in[9];
    const float* blv = (const float*)d_in[10];
    float* out = (float*)d_out;

    const int* srcv = ei;            // edge_index[0]
    const int* dstv = ei + E_EDGES;  // edge_index[1]

    char* p = (char*)d_ws;
    auto carve = [&](size_t bytes) -> void* {
        void* q = (void*)p;
        p += (bytes + 255) & ~(size_t)255;
        return q;
    };
    int* cnt      = (int*)carve(N_NODES * 4);
    int* row_ptr  = (int*)carve((N_NODES + 1) * 4);
    int* cursor   = (int*)carve(N_NODES * 4);
    int* csr_src  = (int*)carve(E_EDGES * 4);
    float* dinv   = (float*)carve(N_NODES * 4);
    unsigned short* xh   = (unsigned short*)carve((size_t)N_NODES * F_IN * 2);
    unsigned short* xl   = (unsigned short*)carve((size_t)N_NODES * F_IN * 2);
    unsigned short* w1th = (unsigned short*)carve((size_t)F_IN * H_DIM * 2);
    unsigned short* w1tl = (unsigned short*)carve((size_t)F_IN * H_DIM * 2);
    unsigned short* w2th = (unsigned short*)carve((size_t)H_DIM * O_DIM * 2);
    unsigned short* w2tl = (unsigned short*)carve((size_t)H_DIM * O_DIM * 2);
    unsigned short* g1b  = (unsigned short*)carve((size_t)N_NODES * H_DIM * 2);
    unsigned short* hh   = (unsigned short*)carve((size_t)N_NODES * H_DIM * 2);
    unsigned short* hl   = (unsigned short*)carve((size_t)N_NODES * H_DIM * 2);
    unsigned short* g2b  = (unsigned short*)carve((size_t)N_NODES * O_DIM * 2);
    unsigned short* zrh  = (unsigned short*)carve((size_t)N_NODES * C_DIM * 2);
    unsigned short* zrl  = (unsigned short*)carve((size_t)N_NODES * C_DIM * 2);

    float* mu_out = out + (size_t)N_NODES * N_NODES;
    float* lv_out = mu_out + (size_t)N_NODES * C_DIM;

    // ---- 1. cooperative CSR build ----
    {
        void* args[] = {(void*)&srcv, (void*)&dstv, (void*)&cnt, (void*)&row_ptr,
                        (void*)&cursor, (void*)&csr_src, (void*)&dinv};
        hipLaunchCooperativeKernel((const void*)csr_build_kernel,
                                   dim3(256), dim3(256), args, 0, stream);
    }

    // ---- 2. fused splits ----
    {
        const int total = N_NODES * F_IN / 4 + F_IN * H_DIM + H_DIM * O_DIM;
        split_all_kernel<<<(total + 255) / 256, 256, 0, stream>>>(
            x, xh, xl, W1, w1th, w1tl, W2, w2th, w2tl);
    }

    // ---- 3. layer 1 GEMM: g1b = bf16(dinv*(x@W1)) ----
    {
        dim3 grid(H_DIM / 64, N_NODES / 128);  // MW=4 (128 rows/block), NW=2 (64 cols/block)
        gemm_mfma_kernel<H_DIM, F_IN, 4, 2><<<grid, 256, 0, stream>>>(
            xh, xl, w1th, w1tl, dinv, g1b);
    }

    // ---- 4. gather 1 -> h (bf16 hi/lo) ----
    gather1_kernel<<<N_NODES / 4, 256, 0, stream>>>(g1b, row_ptr, csr_src, dinv, b1, hh, hl);

    // ---- 5. layer 2 GEMM: g2b = bf16(dinv*(h@W2)) ----
    {
        dim3 grid(O_DIM / 64, N_NODES / 64);   // MW=2 (64 rows/block), NW=2 (64 cols/block)
        gemm_mfma_kernel<O_DIM, H_DIM, 2, 2><<<grid, 256, 0, stream>>>(
            hh, hl, w2th, w2tl, dinv, g2b);
    }

    // ---- 6. fused gather 2 + head ----
    gather_head_kernel<<<N_NODES, 128, 0, stream>>>(
        g2b, row_ptr, csr_src, dinv, b2, Wmu, bmu, Wlv, blv, eps,
        mu_out, lv_out, zrh, zrl);

    // ---- 7. adjacency reconstruction ----
    {
        dim3 grid(N_NODES / 128, N_NODES / 128);
        adj_mfma_kernel<<<grid, 256, 0, stream>>>(zrh, zrl, out);
    }
}

// Round 5
// 216.257 us; speedup vs baseline: 1.3798x; 1.3798x over previous
//
#include <hip/hip_runtime.h>
#include <hip/hip_bf16.h>

#define N_NODES 8192
#define F_IN    512
#define H_DIM   256
#define O_DIM   128
#define C_DIM   64
#define E_EDGES 262144

typedef __attribute__((ext_vector_type(8))) short bf16x8;
typedef __attribute__((ext_vector_type(4))) float f32x4;

__device__ inline unsigned short f2bf(float v) {
    __hip_bfloat16 h = __float2bfloat16(v);
    return *reinterpret_cast<unsigned short*>(&h);
}
__device__ inline float bf2f(unsigned short u) {
    return __uint_as_float((unsigned)u << 16);
}
__device__ inline void split2(float v, unsigned short& hi, unsigned short& lo) {
    hi = f2bf(v);
    lo = f2bf(v - bf2f(hi));
}
__device__ inline float4 bf4_to_f4(ushort4 u) {
    float4 f;
    f.x = bf2f(u.x); f.y = bf2f(u.y); f.z = bf2f(u.z); f.w = bf2f(u.w);
    return f;
}

// ---------------- CSR build (4 small kernels) ----------------
__global__ __launch_bounds__(256) void zero_cnt_kernel(int* __restrict__ cnt) {
    int i = blockIdx.x * 256 + threadIdx.x;
    if (i < N_NODES) cnt[i] = 0;
}

__global__ __launch_bounds__(256) void hist_kernel(const int* __restrict__ dst,
                                                   int* __restrict__ cnt) {
    int e = blockIdx.x * 256 + threadIdx.x;
    if (e < E_EDGES) atomicAdd(&cnt[dst[e]], 1);
}

__global__ __launch_bounds__(1024) void scan_kernel(const int* __restrict__ cnt,
                                                    int* __restrict__ row_ptr,
                                                    int* __restrict__ cursor,
                                                    float* __restrict__ dinv) {
    __shared__ int partial[1024];
    int t = threadIdx.x;
    int base = t * 8;
    int c[8];
    int s = 0;
#pragma unroll
    for (int j = 0; j < 8; ++j) { c[j] = cnt[base + j]; s += c[j]; }
    partial[t] = s;
    __syncthreads();
    for (int off = 1; off < 1024; off <<= 1) {
        int v = 0;
        if (t >= off) v = partial[t - off];
        __syncthreads();
        if (t >= off) partial[t] += v;
        __syncthreads();
    }
    int ex = (t == 0) ? 0 : partial[t - 1];
#pragma unroll
    for (int j = 0; j < 8; ++j) {
        row_ptr[base + j] = ex;
        cursor[base + j] = ex;
        ex += c[j];
        dinv[base + j] = rsqrtf((float)c[j] + 1.0f);
    }
    if (t == 1023) row_ptr[N_NODES] = ex;
}

__global__ __launch_bounds__(256) void fill_kernel(const int* __restrict__ srcv,
                                                   const int* __restrict__ dstv,
                                                   int* __restrict__ cursor,
                                                   int* __restrict__ csr_src) {
    int e = blockIdx.x * 256 + threadIdx.x;
    if (e < E_EDGES) {
        int d = dstv[e];
        int pos = atomicAdd(&cursor[d], 1);
        csr_src[pos] = srcv[e];
    }
}

// ---------------- fused split: x -> xh/xl ; W1 -> W1^T hi/lo ; W2 -> W2^T hi/lo ----------------
__global__ __launch_bounds__(256) void split_all_kernel(
    const float* __restrict__ x, unsigned short* __restrict__ xh, unsigned short* __restrict__ xl,
    const float* __restrict__ W1, unsigned short* __restrict__ w1th, unsigned short* __restrict__ w1tl,
    const float* __restrict__ W2, unsigned short* __restrict__ w2th, unsigned short* __restrict__ w2tl)
{
    const int NX4 = N_NODES * F_IN / 4;       // 1048576 float4 of x
    const int NW1 = F_IN * H_DIM;             // 131072
    const int NW2 = H_DIM * O_DIM;            // 32768
    int idx = blockIdx.x * 256 + threadIdx.x;
    if (idx < NX4) {
        float4 v = ((const float4*)x)[idx];
        ushort4 h, l;
        split2(v.x, h.x, l.x);
        split2(v.y, h.y, l.y);
        split2(v.z, h.z, l.z);
        split2(v.w, h.w, l.w);
        ((ushort4*)xh)[idx] = h;
        ((ushort4*)xl)[idx] = l;
    } else if (idx < NX4 + NW1) {
        int j = idx - NX4;
        int k = j / H_DIM, n = j % H_DIM;
        unsigned short h, l;
        split2(W1[j], h, l);
        w1th[n * F_IN + k] = h;
        w1tl[n * F_IN + k] = l;
    } else if (idx < NX4 + NW1 + NW2) {
        int j = idx - NX4 - NW1;
        int k = j / O_DIM, n = j % O_DIM;
        unsigned short h, l;
        split2(W2[j], h, l);
        w2th[n * H_DIM + k] = h;
        w2tl[n * H_DIM + k] = l;
    }
}

// ---------------- split-bf16 MFMA GEMM: out = dinv ⊙ (A @ Bt^T), bf16 output ----------------
template<int N, int K, int MW, int NW>
__global__ __launch_bounds__(256) void gemm_mfma_kernel(
    const unsigned short* __restrict__ Ah, const unsigned short* __restrict__ Al,
    const unsigned short* __restrict__ Bth, const unsigned short* __restrict__ Btl,
    const float* __restrict__ dinv, unsigned short* __restrict__ out)
{
    const int tid = threadIdx.x;
    const int lane = tid & 63;
    const int wid = tid >> 6;
    const int r = lane & 15;
    const int kg = lane >> 4;
    const int m0 = blockIdx.y * (2 * MW * 16) + (wid >> 1) * (MW * 16);
    const int n0 = blockIdx.x * (2 * NW * 16) + (wid & 1) * (NW * 16);

    f32x4 acc[MW][NW];
#pragma unroll
    for (int mi = 0; mi < MW; ++mi)
#pragma unroll
        for (int ni = 0; ni < NW; ++ni) acc[mi][ni] = (f32x4){0.f, 0.f, 0.f, 0.f};

    for (int k0 = 0; k0 < K; k0 += 32) {
        const int kof = k0 + kg * 8;
        bf16x8 ah[MW], al[MW], bh[NW], bl[NW];
#pragma unroll
        for (int mi = 0; mi < MW; ++mi) {
            size_t off = (size_t)(m0 + mi * 16 + r) * K + kof;
            ah[mi] = *(const bf16x8*)(Ah + off);
            al[mi] = *(const bf16x8*)(Al + off);
        }
#pragma unroll
        for (int ni = 0; ni < NW; ++ni) {
            size_t off = (size_t)(n0 + ni * 16 + r) * K + kof;
            bh[ni] = *(const bf16x8*)(Bth + off);
            bl[ni] = *(const bf16x8*)(Btl + off);
        }
#pragma unroll
        for (int mi = 0; mi < MW; ++mi)
#pragma unroll
            for (int ni = 0; ni < NW; ++ni) {
                acc[mi][ni] = __builtin_amdgcn_mfma_f32_16x16x32_bf16(ah[mi], bh[ni], acc[mi][ni], 0, 0, 0);
                acc[mi][ni] = __builtin_amdgcn_mfma_f32_16x16x32_bf16(ah[mi], bl[ni], acc[mi][ni], 0, 0, 0);
                acc[mi][ni] = __builtin_amdgcn_mfma_f32_16x16x32_bf16(al[mi], bh[ni], acc[mi][ni], 0, 0, 0);
            }
    }

#pragma unroll
    for (int mi = 0; mi < MW; ++mi) {
        int rowb = m0 + mi * 16 + kg * 4;
        float di[4];
#pragma unroll
        for (int i = 0; i < 4; ++i) di[i] = dinv[rowb + i];
#pragma unroll
        for (int ni = 0; ni < NW; ++ni) {
            int col = n0 + ni * 16 + r;
#pragma unroll
            for (int i = 0; i < 4; ++i)
                out[(size_t)(rowb + i) * N + col] = f2bf(di[i] * acc[mi][ni][i]);
        }
    }
}

// ---------------- gather layer 1 (bf16 g1): h = relu(dinv*(sum+self)+b), write hi/lo split ----------------
__global__ __launch_bounds__(256) void gather1_kernel(
    const unsigned short* __restrict__ g,   // [N_NODES][256] bf16
    const int* __restrict__ row_ptr, const int* __restrict__ csr_src,
    const float* __restrict__ dinv, const float* __restrict__ b,
    unsigned short* __restrict__ hh, unsigned short* __restrict__ hl)
{
    const int wid = threadIdx.x >> 6;
    const int lane = threadIdx.x & 63;
    const int node = blockIdx.x * 4 + wid;
    if (node >= N_NODES) return;

    const ushort4* G4 = (const ushort4*)g;  // row stride 64 ushort4
    const int beg = row_ptr[node];
    const int end = row_ptr[node + 1];

    float4 acc = bf4_to_f4(G4[(size_t)node * 64 + lane]);  // self
    float4 acc2 = make_float4(0.f, 0.f, 0.f, 0.f);

    int e = beg;
    for (; e + 4 <= end; e += 4) {
        int s0 = csr_src[e], s1 = csr_src[e + 1], s2 = csr_src[e + 2], s3 = csr_src[e + 3];
        float4 v0 = bf4_to_f4(G4[(size_t)s0 * 64 + lane]);
        float4 v1 = bf4_to_f4(G4[(size_t)s1 * 64 + lane]);
        float4 v2 = bf4_to_f4(G4[(size_t)s2 * 64 + lane]);
        float4 v3 = bf4_to_f4(G4[(size_t)s3 * 64 + lane]);
        acc.x += v0.x + v1.x; acc.y += v0.y + v1.y;
        acc.z += v0.z + v1.z; acc.w += v0.w + v1.w;
        acc2.x += v2.x + v3.x; acc2.y += v2.y + v3.y;
        acc2.z += v2.z + v3.z; acc2.w += v2.w + v3.w;
    }
    for (; e < end; ++e) {
        float4 v0 = bf4_to_f4(G4[(size_t)csr_src[e] * 64 + lane]);
        acc.x += v0.x; acc.y += v0.y; acc.z += v0.z; acc.w += v0.w;
    }
    acc.x += acc2.x; acc.y += acc2.y; acc.z += acc2.z; acc.w += acc2.w;

    float di = dinv[node];
    const float4 bv = ((const float4*)b)[lane];
    float4 rr;
    rr.x = di * acc.x + bv.x;
    rr.y = di * acc.y + bv.y;
    rr.z = di * acc.z + bv.z;
    rr.w = di * acc.w + bv.w;
    rr.x = rr.x > 0.f ? rr.x : 0.f;
    rr.y = rr.y > 0.f ? rr.y : 0.f;
    rr.z = rr.z > 0.f ? rr.z : 0.f;
    rr.w = rr.w > 0.f ? rr.w : 0.f;

    ushort4 h, l;
    split2(rr.x, h.x, l.x);
    split2(rr.y, h.y, l.y);
    split2(rr.z, h.z, l.z);
    split2(rr.w, h.w, l.w);
    ((ushort4*)hh)[(size_t)node * 64 + lane] = h;
    ((ushort4*)hl)[(size_t)node * 64 + lane] = l;
}

// ---------------- fused gather layer 2 + head: z -> mu, logvar, zr(hi/lo) ----------------
__global__ __launch_bounds__(128) void gather_head_kernel(
    const unsigned short* __restrict__ g2,  // [N_NODES][128] bf16
    const int* __restrict__ row_ptr, const int* __restrict__ csr_src,
    const float* __restrict__ dinv, const float* __restrict__ b2,
    const float* __restrict__ Wmu, const float* __restrict__ bmu,
    const float* __restrict__ Wlv, const float* __restrict__ blv,
    const float* __restrict__ eps,
    float* __restrict__ mu_out, float* __restrict__ lv_out,
    unsigned short* __restrict__ zrh, unsigned short* __restrict__ zrl)
{
    __shared__ float zs[O_DIM];
    __shared__ float mu_s[C_DIM];
    __shared__ float lv_s[C_DIM];
    const int node = blockIdx.x;
    const int t = threadIdx.x;

    const int beg = row_ptr[node];
    const int end = row_ptr[node + 1];

    float acc = bf2f(g2[(size_t)node * O_DIM + t]);  // self
    float acc2 = 0.f;
    int e = beg;
    for (; e + 4 <= end; e += 4) {
        int s0 = csr_src[e], s1 = csr_src[e + 1], s2 = csr_src[e + 2], s3 = csr_src[e + 3];
        acc  += bf2f(g2[(size_t)s0 * O_DIM + t]) + bf2f(g2[(size_t)s1 * O_DIM + t]);
        acc2 += bf2f(g2[(size_t)s2 * O_DIM + t]) + bf2f(g2[(size_t)s3 * O_DIM + t]);
    }
    for (; e < end; ++e) acc += bf2f(g2[(size_t)csr_src[e] * O_DIM + t]);
    acc += acc2;

    zs[t] = dinv[node] * acc + b2[t];
    __syncthreads();

    const int c = t & 63;
    const float* W = (t < 64) ? Wmu : Wlv;
    float s = 0.f;
#pragma unroll 8
    for (int k = 0; k < O_DIM; ++k) s += zs[k] * W[k * C_DIM + c];
    if (t < 64) {
        s += bmu[c];
        mu_out[(size_t)node * C_DIM + c] = s;
        mu_s[c] = s;
    } else {
        s += blv[c];
        lv_out[(size_t)node * C_DIM + c] = s;
        lv_s[c] = s;
    }
    __syncthreads();
    if (t < 64) {
        float stdv = __expf(0.5f * lv_s[c]);
        float v = mu_s[c] + eps[(size_t)node * C_DIM + c] * stdv;
        unsigned short h, l;
        split2(v, h, l);
        zrh[(size_t)node * C_DIM + c] = h;
        zrl[(size_t)node * C_DIM + c] = l;
    }
}

// ---------------- adj = sigmoid(zr @ zr^T) via split-bf16 MFMA ----------------
__global__ __launch_bounds__(256) void adj_mfma_kernel(
    const unsigned short* __restrict__ Zh, const unsigned short* __restrict__ Zl,
    float* __restrict__ out)
{
    const int tid = threadIdx.x;
    const int lane = tid & 63;
    const int wid = tid >> 6;
    const int r = lane & 15;
    const int kg = lane >> 4;
    const int m0 = blockIdx.y * 128 + (wid >> 1) * 64;
    const int n0 = blockIdx.x * 128 + (wid & 1) * 64;

    bf16x8 ah[4][2], al[4][2];
#pragma unroll
    for (int mi = 0; mi < 4; ++mi)
#pragma unroll
        for (int ks = 0; ks < 2; ++ks) {
            size_t off = (size_t)(m0 + mi * 16 + r) * C_DIM + ks * 32 + kg * 8;
            ah[mi][ks] = *(const bf16x8*)(Zh + off);
            al[mi][ks] = *(const bf16x8*)(Zl + off);
        }

    f32x4 acc[4][4];
#pragma unroll
    for (int mi = 0; mi < 4; ++mi)
#pragma unroll
        for (int ni = 0; ni < 4; ++ni) acc[mi][ni] = (f32x4){0.f, 0.f, 0.f, 0.f};

#pragma unroll
    for (int ni = 0; ni < 4; ++ni) {
        bf16x8 bh[2], bl[2];
#pragma unroll
        for (int ks = 0; ks < 2; ++ks) {
            size_t off = (size_t)(n0 + ni * 16 + r) * C_DIM + ks * 32 + kg * 8;
            bh[ks] = *(const bf16x8*)(Zh + off);
            bl[ks] = *(const bf16x8*)(Zl + off);
        }
#pragma unroll
        for (int mi = 0; mi < 4; ++mi)
#pragma unroll
            for (int ks = 0; ks < 2; ++ks) {
                acc[mi][ni] = __builtin_amdgcn_mfma_f32_16x16x32_bf16(ah[mi][ks], bh[ks], acc[mi][ni], 0, 0, 0);
                acc[mi][ni] = __builtin_amdgcn_mfma_f32_16x16x32_bf16(ah[mi][ks], bl[ks], acc[mi][ni], 0, 0, 0);
                acc[mi][ni] = __builtin_amdgcn_mfma_f32_16x16x32_bf16(al[mi][ks], bh[ks], acc[mi][ni], 0, 0, 0);
            }
    }

#pragma unroll
    for (int mi = 0; mi < 4; ++mi) {
        int rowb = m0 + mi * 16 + kg * 4;
#pragma unroll
        for (int ni = 0; ni < 4; ++ni) {
            int col = n0 + ni * 16 + r;
#pragma unroll
            for (int i = 0; i < 4; ++i) {
                float v = acc[mi][ni][i];
                float e = __expf(-v);
                out[(size_t)(rowb + i) * N_NODES + col] = __builtin_amdgcn_rcpf(1.0f + e);
            }
        }
    }
}

extern "C" void kernel_launch(void* const* d_in, const int* in_sizes, int n_in,
                              void* d_out, int out_size, void* d_ws, size_t ws_size,
                              hipStream_t stream) {
    const float* x   = (const float*)d_in[0];
    const int*   ei  = (const int*)  d_in[1];
    const float* eps = (const float*)d_in[2];
    const float* W1  = (const float*)d_in[3];
    const float* b1  = (const float*)d_in[4];
    const float* W2  = (const float*)d_in[5];
    const float* b2  = (const float*)d_in[6];
    const float* Wmu = (const float*)d_in[7];
    const float* bmu = (const float*)d_in[8];
    const float* Wlv = (const float*)d_in[9];
    const float* blv = (const float*)d_in[10];
    float* out = (float*)d_out;

    const int* srcv = ei;            // edge_index[0]
    const int* dstv = ei + E_EDGES;  // edge_index[1]

    char* p = (char*)d_ws;
    auto carve = [&](size_t bytes) -> void* {
        void* q = (void*)p;
        p += (bytes + 255) & ~(size_t)255;
        return q;
    };
    int* cnt      = (int*)carve(N_NODES * 4);
    int* row_ptr  = (int*)carve((N_NODES + 1) * 4);
    int* cursor   = (int*)carve(N_NODES * 4);
    int* csr_src  = (int*)carve(E_EDGES * 4);
    float* dinv   = (float*)carve(N_NODES * 4);
    unsigned short* xh   = (unsigned short*)carve((size_t)N_NODES * F_IN * 2);
    unsigned short* xl   = (unsigned short*)carve((size_t)N_NODES * F_IN * 2);
    unsigned short* w1th = (unsigned short*)carve((size_t)F_IN * H_DIM * 2);
    unsigned short* w1tl = (unsigned short*)carve((size_t)F_IN * H_DIM * 2);
    unsigned short* w2th = (unsigned short*)carve((size_t)H_DIM * O_DIM * 2);
    unsigned short* w2tl = (unsigned short*)carve((size_t)H_DIM * O_DIM * 2);
    unsigned short* g1b  = (unsigned short*)carve((size_t)N_NODES * H_DIM * 2);
    unsigned short* hh   = (unsigned short*)carve((size_t)N_NODES * H_DIM * 2);
    unsigned short* hl   = (unsigned short*)carve((size_t)N_NODES * H_DIM * 2);
    unsigned short* g2b  = (unsigned short*)carve((size_t)N_NODES * O_DIM * 2);
    unsigned short* zrh  = (unsigned short*)carve((size_t)N_NODES * C_DIM * 2);
    unsigned short* zrl  = (unsigned short*)carve((size_t)N_NODES * C_DIM * 2);

    float* mu_out = out + (size_t)N_NODES * N_NODES;
    float* lv_out = mu_out + (size_t)N_NODES * C_DIM;

    // ---- CSR build + dinv (plain kernels; cooperative launch cost ~40us in graph) ----
    zero_cnt_kernel<<<N_NODES / 256, 256, 0, stream>>>(cnt);
    hist_kernel<<<E_EDGES / 256, 256, 0, stream>>>(dstv, cnt);
    scan_kernel<<<1, 1024, 0, stream>>>(cnt, row_ptr, cursor, dinv);
    fill_kernel<<<E_EDGES / 256, 256, 0, stream>>>(srcv, dstv, cursor, csr_src);

    // ---- fused splits ----
    {
        const int total = N_NODES * F_IN / 4 + F_IN * H_DIM + H_DIM * O_DIM;
        split_all_kernel<<<(total + 255) / 256, 256, 0, stream>>>(
            x, xh, xl, W1, w1th, w1tl, W2, w2th, w2tl);
    }

    // ---- layer 1 GEMM: g1b = bf16(dinv*(x@W1)) ----
    {
        dim3 grid(H_DIM / 64, N_NODES / 128);  // MW=4, NW=2
        gemm_mfma_kernel<H_DIM, F_IN, 4, 2><<<grid, 256, 0, stream>>>(
            xh, xl, w1th, w1tl, dinv, g1b);
    }

    // ---- gather 1 -> h (bf16 hi/lo) ----
    gather1_kernel<<<N_NODES / 4, 256, 0, stream>>>(g1b, row_ptr, csr_src, dinv, b1, hh, hl);

    // ---- layer 2 GEMM: g2b = bf16(dinv*(h@W2)) ----
    {
        dim3 grid(O_DIM / 64, N_NODES / 64);   // MW=2, NW=2
        gemm_mfma_kernel<O_DIM, H_DIM, 2, 2><<<grid, 256, 0, stream>>>(
            hh, hl, w2th, w2tl, dinv, g2b);
    }

    // ---- fused gather 2 + head ----
    gather_head_kernel<<<N_NODES, 128, 0, stream>>>(
        g2b, row_ptr, csr_src, dinv, b2, Wmu, bmu, Wlv, blv, eps,
        mu_out, lv_out, zrh, zrl);

    // ---- adjacency reconstruction ----
    {
        dim3 grid(N_NODES / 128, N_NODES / 128);
        adj_mfma_kernel<<<grid, 256, 0, stream>>>(zrh, zrl, out);
    }
}

// Round 6
// 207.661 us; speedup vs baseline: 1.4369x; 1.0414x over previous
//
#include <hip/hip_runtime.h>
#include <hip/hip_bf16.h>

#define N_NODES 8192
#define F_IN    512
#define H_DIM   256
#define O_DIM   128
#define C_DIM   64
#define E_EDGES 262144

typedef __attribute__((ext_vector_type(8))) short bf16x8;
typedef __attribute__((ext_vector_type(4))) float f32x4;

__device__ inline unsigned short f2bf(float v) {
    __hip_bfloat16 h = __float2bfloat16(v);
    return *reinterpret_cast<unsigned short*>(&h);
}
__device__ inline float bf2f(unsigned short u) {
    return __uint_as_float((unsigned)u << 16);
}
__device__ inline void split2(float v, unsigned short& hi, unsigned short& lo) {
    hi = f2bf(v);
    lo = f2bf(v - bf2f(hi));
}
__device__ inline float4 bf4_to_f4(ushort4 u) {
    float4 f;
    f.x = bf2f(u.x); f.y = bf2f(u.y); f.z = bf2f(u.z); f.w = bf2f(u.w);
    return f;
}

// ---------------- fused split (+ cnt zeroing): x -> xh/xl ; W1,W2 -> transposed hi/lo ----------------
__global__ __launch_bounds__(256) void split_all_kernel(
    const float* __restrict__ x, unsigned short* __restrict__ xh, unsigned short* __restrict__ xl,
    const float* __restrict__ W1, unsigned short* __restrict__ w1th, unsigned short* __restrict__ w1tl,
    const float* __restrict__ W2, unsigned short* __restrict__ w2th, unsigned short* __restrict__ w2tl,
    int* __restrict__ cnt)
{
    const int NX4 = N_NODES * F_IN / 4;       // 1048576 float4 of x
    const int NW1 = F_IN * H_DIM;             // 131072
    const int NW2 = H_DIM * O_DIM;            // 32768
    int idx = blockIdx.x * 256 + threadIdx.x;
    if (idx < N_NODES) cnt[idx] = 0;          // folded zero_cnt
    if (idx < NX4) {
        float4 v = ((const float4*)x)[idx];
        ushort4 h, l;
        split2(v.x, h.x, l.x);
        split2(v.y, h.y, l.y);
        split2(v.z, h.z, l.z);
        split2(v.w, h.w, l.w);
        ((ushort4*)xh)[idx] = h;
        ((ushort4*)xl)[idx] = l;
    } else if (idx < NX4 + NW1) {
        int j = idx - NX4;
        int k = j / H_DIM, n = j % H_DIM;
        unsigned short h, l;
        split2(W1[j], h, l);
        w1th[n * F_IN + k] = h;
        w1tl[n * F_IN + k] = l;
    } else if (idx < NX4 + NW1 + NW2) {
        int j = idx - NX4 - NW1;
        int k = j / O_DIM, n = j % O_DIM;
        unsigned short h, l;
        split2(W2[j], h, l);
        w2th[n * H_DIM + k] = h;
        w2tl[n * H_DIM + k] = l;
    }
}

// ---------------- CSR build ----------------
__global__ __launch_bounds__(256) void hist_kernel(const int* __restrict__ dst,
                                                   int* __restrict__ cnt) {
    int e = blockIdx.x * 256 + threadIdx.x;
    if (e < E_EDGES) atomicAdd(&cnt[dst[e]], 1);
}

// single block, 1024 threads: shfl-based hierarchical exclusive scan + dinv
__global__ __launch_bounds__(1024) void scan_kernel(const int* __restrict__ cnt,
                                                    int* __restrict__ row_ptr,
                                                    int* __restrict__ cursor,
                                                    float* __restrict__ dinv) {
    __shared__ int wsum[16];
    const int t = threadIdx.x;
    const int lane = t & 63;
    const int wv = t >> 6;
    const int base = t * 8;
    int c[8];
    int s = 0;
#pragma unroll
    for (int j = 0; j < 8; ++j) { c[j] = cnt[base + j]; s += c[j]; }
    // inclusive wave scan of s
    int ssc = s;
#pragma unroll
    for (int d = 1; d < 64; d <<= 1) {
        int v = __shfl_up(ssc, d, 64);
        if (lane >= d) ssc += v;
    }
    if (lane == 63) wsum[wv] = ssc;
    __syncthreads();
    if (t < 16) {
        int v = wsum[t];
        int sc = v;
#pragma unroll
        for (int d = 1; d < 16; d <<= 1) {
            int u = __shfl_up(sc, d, 64);
            if (t >= d) sc += u;
        }
        wsum[t] = sc - v;  // exclusive wave prefix
    }
    __syncthreads();
    int ex = wsum[wv] + (ssc - s);  // exclusive prefix for this thread's chunk
#pragma unroll
    for (int j = 0; j < 8; ++j) {
        row_ptr[base + j] = ex;
        cursor[base + j] = ex;
        ex += c[j];
        dinv[base + j] = rsqrtf((float)c[j] + 1.0f);
    }
    if (t == 1023) row_ptr[N_NODES] = ex;
}

__global__ __launch_bounds__(256) void fill_kernel(const int* __restrict__ srcv,
                                                   const int* __restrict__ dstv,
                                                   int* __restrict__ cursor,
                                                   int* __restrict__ csr_src) {
    int e = blockIdx.x * 256 + threadIdx.x;
    if (e < E_EDGES) {
        int d = dstv[e];
        int pos = atomicAdd(&cursor[d], 1);
        csr_src[pos] = srcv[e];
    }
}

// ---------------- split-bf16 MFMA GEMM with register double-buffered K-loop ----------------
// out = bf16(dinv ⊙ (A @ Bt^T)); wave tile (MW*16)x(NW*16); block = 4 waves 2x2.
#define LOADF(S, koff)                                                          \
    do {                                                                        \
        const int kof_ = (koff) + kg * 8;                                       \
        _Pragma("unroll")                                                       \
        for (int mi = 0; mi < MW; ++mi) {                                       \
            size_t off = (size_t)(m0 + mi * 16 + r) * K + kof_;                 \
            ah##S[mi] = *(const bf16x8*)(Ah + off);                             \
            al##S[mi] = *(const bf16x8*)(Al + off);                             \
        }                                                                       \
        _Pragma("unroll")                                                       \
        for (int ni = 0; ni < NW; ++ni) {                                       \
            size_t off = (size_t)(n0 + ni * 16 + r) * K + kof_;                 \
            bh##S[ni] = *(const bf16x8*)(Bth + off);                            \
            bl##S[ni] = *(const bf16x8*)(Btl + off);                            \
        }                                                                       \
    } while (0)

#define MFMAF(S)                                                                                        \
    do {                                                                                                \
        _Pragma("unroll")                                                                               \
        for (int mi = 0; mi < MW; ++mi)                                                                 \
            _Pragma("unroll")                                                                           \
            for (int ni = 0; ni < NW; ++ni) {                                                           \
                acc[mi][ni] = __builtin_amdgcn_mfma_f32_16x16x32_bf16(ah##S[mi], bh##S[ni], acc[mi][ni], 0, 0, 0); \
                acc[mi][ni] = __builtin_amdgcn_mfma_f32_16x16x32_bf16(ah##S[mi], bl##S[ni], acc[mi][ni], 0, 0, 0); \
                acc[mi][ni] = __builtin_amdgcn_mfma_f32_16x16x32_bf16(al##S[mi], bh##S[ni], acc[mi][ni], 0, 0, 0); \
            }                                                                                           \
    } while (0)

template<int N, int K, int MW, int NW>
__global__ __launch_bounds__(256) void gemm_mfma_kernel(
    const unsigned short* __restrict__ Ah, const unsigned short* __restrict__ Al,
    const unsigned short* __restrict__ Bth, const unsigned short* __restrict__ Btl,
    const float* __restrict__ dinv, unsigned short* __restrict__ out)
{
    const int tid = threadIdx.x;
    const int lane = tid & 63;
    const int wid = tid >> 6;
    const int r = lane & 15;
    const int kg = lane >> 4;
    const int m0 = blockIdx.y * (2 * MW * 16) + (wid >> 1) * (MW * 16);
    const int n0 = blockIdx.x * (2 * NW * 16) + (wid & 1) * (NW * 16);

    f32x4 acc[MW][NW];
#pragma unroll
    for (int mi = 0; mi < MW; ++mi)
#pragma unroll
        for (int ni = 0; ni < NW; ++ni) acc[mi][ni] = (f32x4){0.f, 0.f, 0.f, 0.f};

    bf16x8 ahA[MW], alA[MW], bhA[NW], blA[NW];
    bf16x8 ahB[MW], alB[MW], bhB[NW], blB[NW];

    LOADF(A, 0);
    for (int k0 = 0; k0 < K; k0 += 64) {
        LOADF(B, k0 + 32);           // prefetch second half-step
        MFMAF(A);
        if (k0 + 64 < K) LOADF(A, k0 + 64);  // prefetch next iter
        MFMAF(B);
    }

#pragma unroll
    for (int mi = 0; mi < MW; ++mi) {
        int rowb = m0 + mi * 16 + kg * 4;
        float di[4];
#pragma unroll
        for (int i = 0; i < 4; ++i) di[i] = dinv[rowb + i];
#pragma unroll
        for (int ni = 0; ni < NW; ++ni) {
            int col = n0 + ni * 16 + r;
#pragma unroll
            for (int i = 0; i < 4; ++i)
                out[(size_t)(rowb + i) * N + col] = f2bf(di[i] * acc[mi][ni][i]);
        }
    }
}

// ---------------- gather layer 1 (bf16 g1): h = relu(dinv*(sum+self)+b), write hi/lo split ----------------
__global__ __launch_bounds__(256) void gather1_kernel(
    const unsigned short* __restrict__ g,   // [N_NODES][256] bf16
    const int* __restrict__ row_ptr, const int* __restrict__ csr_src,
    const float* __restrict__ dinv, const float* __restrict__ b,
    unsigned short* __restrict__ hh, unsigned short* __restrict__ hl)
{
    const int wid = threadIdx.x >> 6;
    const int lane = threadIdx.x & 63;
    const int node = blockIdx.x * 4 + wid;
    if (node >= N_NODES) return;

    const ushort4* G4 = (const ushort4*)g;  // row stride 64 ushort4
    const int beg = row_ptr[node];
    const int end = row_ptr[node + 1];

    float4 acc = bf4_to_f4(G4[(size_t)node * 64 + lane]);  // self
    float4 acc2 = make_float4(0.f, 0.f, 0.f, 0.f);

    int e = beg;
    for (; e + 4 <= end; e += 4) {
        int s0 = csr_src[e], s1 = csr_src[e + 1], s2 = csr_src[e + 2], s3 = csr_src[e + 3];
        float4 v0 = bf4_to_f4(G4[(size_t)s0 * 64 + lane]);
        float4 v1 = bf4_to_f4(G4[(size_t)s1 * 64 + lane]);
        float4 v2 = bf4_to_f4(G4[(size_t)s2 * 64 + lane]);
        float4 v3 = bf4_to_f4(G4[(size_t)s3 * 64 + lane]);
        acc.x += v0.x + v1.x; acc.y += v0.y + v1.y;
        acc.z += v0.z + v1.z; acc.w += v0.w + v1.w;
        acc2.x += v2.x + v3.x; acc2.y += v2.y + v3.y;
        acc2.z += v2.z + v3.z; acc2.w += v2.w + v3.w;
    }
    for (; e < end; ++e) {
        float4 v0 = bf4_to_f4(G4[(size_t)csr_src[e] * 64 + lane]);
        acc.x += v0.x; acc.y += v0.y; acc.z += v0.z; acc.w += v0.w;
    }
    acc.x += acc2.x; acc.y += acc2.y; acc.z += acc2.z; acc.w += acc2.w;

    float di = dinv[node];
    const float4 bv = ((const float4*)b)[lane];
    float4 rr;
    rr.x = di * acc.x + bv.x;
    rr.y = di * acc.y + bv.y;
    rr.z = di * acc.z + bv.z;
    rr.w = di * acc.w + bv.w;
    rr.x = rr.x > 0.f ? rr.x : 0.f;
    rr.y = rr.y > 0.f ? rr.y : 0.f;
    rr.z = rr.z > 0.f ? rr.z : 0.f;
    rr.w = rr.w > 0.f ? rr.w : 0.f;

    ushort4 h, l;
    split2(rr.x, h.x, l.x);
    split2(rr.y, h.y, l.y);
    split2(rr.z, h.z, l.z);
    split2(rr.w, h.w, l.w);
    ((ushort4*)hh)[(size_t)node * 64 + lane] = h;
    ((ushort4*)hl)[(size_t)node * 64 + lane] = l;
}

// ---------------- fused gather layer 2 + head: z -> mu, logvar, zr(hi/lo) ----------------
__global__ __launch_bounds__(128) void gather_head_kernel(
    const unsigned short* __restrict__ g2,  // [N_NODES][128] bf16
    const int* __restrict__ row_ptr, const int* __restrict__ csr_src,
    const float* __restrict__ dinv, const float* __restrict__ b2,
    const float* __restrict__ Wmu, const float* __restrict__ bmu,
    const float* __restrict__ Wlv, const float* __restrict__ blv,
    const float* __restrict__ eps,
    float* __restrict__ mu_out, float* __restrict__ lv_out,
    unsigned short* __restrict__ zrh, unsigned short* __restrict__ zrl)
{
    __shared__ float zs[O_DIM];
    __shared__ float mu_s[C_DIM];
    __shared__ float lv_s[C_DIM];
    const int node = blockIdx.x;
    const int t = threadIdx.x;

    const int beg = row_ptr[node];
    const int end = row_ptr[node + 1];

    float acc = bf2f(g2[(size_t)node * O_DIM + t]);  // self
    float acc2 = 0.f;
    int e = beg;
    for (; e + 4 <= end; e += 4) {
        int s0 = csr_src[e], s1 = csr_src[e + 1], s2 = csr_src[e + 2], s3 = csr_src[e + 3];
        acc  += bf2f(g2[(size_t)s0 * O_DIM + t]) + bf2f(g2[(size_t)s1 * O_DIM + t]);
        acc2 += bf2f(g2[(size_t)s2 * O_DIM + t]) + bf2f(g2[(size_t)s3 * O_DIM + t]);
    }
    for (; e < end; ++e) acc += bf2f(g2[(size_t)csr_src[e] * O_DIM + t]);
    acc += acc2;

    zs[t] = dinv[node] * acc + b2[t];
    __syncthreads();

    const int c = t & 63;
    const float* W = (t < 64) ? Wmu : Wlv;
    float s = 0.f;
#pragma unroll 8
    for (int k = 0; k < O_DIM; ++k) s += zs[k] * W[k * C_DIM + c];
    if (t < 64) {
        s += bmu[c];
        mu_out[(size_t)node * C_DIM + c] = s;
        mu_s[c] = s;
    } else {
        s += blv[c];
        lv_out[(size_t)node * C_DIM + c] = s;
        lv_s[c] = s;
    }
    __syncthreads();
    if (t < 64) {
        float stdv = __expf(0.5f * lv_s[c]);
        float v = mu_s[c] + eps[(size_t)node * C_DIM + c] * stdv;
        unsigned short h, l;
        split2(v, h, l);
        zrh[(size_t)node * C_DIM + c] = h;
        zrl[(size_t)node * C_DIM + c] = l;
    }
}

// ---------------- adj = sigmoid(zr @ zr^T) via split-bf16 MFMA, nontemporal stores ----------------
__global__ __launch_bounds__(256) void adj_mfma_kernel(
    const unsigned short* __restrict__ Zh, const unsigned short* __restrict__ Zl,
    float* __restrict__ out)
{
    const int tid = threadIdx.x;
    const int lane = tid & 63;
    const int wid = tid >> 6;
    const int r = lane & 15;
    const int kg = lane >> 4;
    const int m0 = blockIdx.y * 128 + (wid >> 1) * 64;
    const int n0 = blockIdx.x * 128 + (wid & 1) * 64;

    bf16x8 ah[4][2], al[4][2];
#pragma unroll
    for (int mi = 0; mi < 4; ++mi)
#pragma unroll
        for (int ks = 0; ks < 2; ++ks) {
            size_t off = (size_t)(m0 + mi * 16 + r) * C_DIM + ks * 32 + kg * 8;
            ah[mi][ks] = *(const bf16x8*)(Zh + off);
            al[mi][ks] = *(const bf16x8*)(Zl + off);
        }

    f32x4 acc[4][4];
#pragma unroll
    for (int mi = 0; mi < 4; ++mi)
#pragma unroll
        for (int ni = 0; ni < 4; ++ni) acc[mi][ni] = (f32x4){0.f, 0.f, 0.f, 0.f};

#pragma unroll
    for (int ni = 0; ni < 4; ++ni) {
        bf16x8 bh[2], bl[2];
#pragma unroll
        for (int ks = 0; ks < 2; ++ks) {
            size_t off = (size_t)(n0 + ni * 16 + r) * C_DIM + ks * 32 + kg * 8;
            bh[ks] = *(const bf16x8*)(Zh + off);
            bl[ks] = *(const bf16x8*)(Zl + off);
        }
#pragma unroll
        for (int mi = 0; mi < 4; ++mi)
#pragma unroll
            for (int ks = 0; ks < 2; ++ks) {
                acc[mi][ni] = __builtin_amdgcn_mfma_f32_16x16x32_bf16(ah[mi][ks], bh[ks], acc[mi][ni], 0, 0, 0);
                acc[mi][ni] = __builtin_amdgcn_mfma_f32_16x16x32_bf16(ah[mi][ks], bl[ks], acc[mi][ni], 0, 0, 0);
                acc[mi][ni] = __builtin_amdgcn_mfma_f32_16x16x32_bf16(al[mi][ks], bh[ks], acc[mi][ni], 0, 0, 0);
            }
    }

#pragma unroll
    for (int mi = 0; mi < 4; ++mi) {
        int rowb = m0 + mi * 16 + kg * 4;
#pragma unroll
        for (int ni = 0; ni < 4; ++ni) {
            int col = n0 + ni * 16 + r;
#pragma unroll
            for (int i = 0; i < 4; ++i) {
                float v = acc[mi][ni][i];
                float e = __expf(-v);
                float sg = __builtin_amdgcn_rcpf(1.0f + e);
                __builtin_nontemporal_store(sg, &out[(size_t)(rowb + i) * N_NODES + col]);
            }
        }
    }
}

extern "C" void kernel_launch(void* const* d_in, const int* in_sizes, int n_in,
                              void* d_out, int out_size, void* d_ws, size_t ws_size,
                              hipStream_t stream) {
    const float* x   = (const float*)d_in[0];
    const int*   ei  = (const int*)  d_in[1];
    const float* eps = (const float*)d_in[2];
    const float* W1  = (const float*)d_in[3];
    const float* b1  = (const float*)d_in[4];
    const float* W2  = (const float*)d_in[5];
    const float* b2  = (const float*)d_in[6];
    const float* Wmu = (const float*)d_in[7];
    const float* bmu = (const float*)d_in[8];
    const float* Wlv = (const float*)d_in[9];
    const float* blv = (const float*)d_in[10];
    float* out = (float*)d_out;

    const int* srcv = ei;            // edge_index[0]
    const int* dstv = ei + E_EDGES;  // edge_index[1]

    char* p = (char*)d_ws;
    auto carve = [&](size_t bytes) -> void* {
        void* q = (void*)p;
        p += (bytes + 255) & ~(size_t)255;
        return q;
    };
    int* cnt      = (int*)carve(N_NODES * 4);
    int* row_ptr  = (int*)carve((N_NODES + 1) * 4);
    int* cursor   = (int*)carve(N_NODES * 4);
    int* csr_src  = (int*)carve(E_EDGES * 4);
    float* dinv   = (float*)carve(N_NODES * 4);
    unsigned short* xh   = (unsigned short*)carve((size_t)N_NODES * F_IN * 2);
    unsigned short* xl   = (unsigned short*)carve((size_t)N_NODES * F_IN * 2);
    unsigned short* w1th = (unsigned short*)carve((size_t)F_IN * H_DIM * 2);
    unsigned short* w1tl = (unsigned short*)carve((size_t)F_IN * H_DIM * 2);
    unsigned short* w2th = (unsigned short*)carve((size_t)H_DIM * O_DIM * 2);
    unsigned short* w2tl = (unsigned short*)carve((size_t)H_DIM * O_DIM * 2);
    unsigned short* g1b  = (unsigned short*)carve((size_t)N_NODES * H_DIM * 2);
    unsigned short* hh   = (unsigned short*)carve((size_t)N_NODES * H_DIM * 2);
    unsigned short* hl   = (unsigned short*)carve((size_t)N_NODES * H_DIM * 2);
    unsigned short* g2b  = (unsigned short*)carve((size_t)N_NODES * O_DIM * 2);
    unsigned short* zrh  = (unsigned short*)carve((size_t)N_NODES * C_DIM * 2);
    unsigned short* zrl  = (unsigned short*)carve((size_t)N_NODES * C_DIM * 2);

    float* mu_out = out + (size_t)N_NODES * N_NODES;
    float* lv_out = mu_out + (size_t)N_NODES * C_DIM;

    // ---- 1. fused splits (+ cnt zero) ----
    {
        const int total = N_NODES * F_IN / 4 + F_IN * H_DIM + H_DIM * O_DIM;
        split_all_kernel<<<(total + 255) / 256, 256, 0, stream>>>(
            x, xh, xl, W1, w1th, w1tl, W2, w2th, w2tl, cnt);
    }

    // ---- 2-4. CSR build + dinv ----
    hist_kernel<<<E_EDGES / 256, 256, 0, stream>>>(dstv, cnt);
    scan_kernel<<<1, 1024, 0, stream>>>(cnt, row_ptr, cursor, dinv);
    fill_kernel<<<E_EDGES / 256, 256, 0, stream>>>(srcv, dstv, cursor, csr_src);

    // ---- 5. layer 1 GEMM: g1b = bf16(dinv*(x@W1)), 64x64 blocks, 512 blocks ----
    {
        dim3 grid(H_DIM / 64, N_NODES / 64);   // MW=2, NW=2
        gemm_mfma_kernel<H_DIM, F_IN, 2, 2><<<grid, 256, 0, stream>>>(
            xh, xl, w1th, w1tl, dinv, g1b);
    }

    // ---- 6. gather 1 -> h (bf16 hi/lo) ----
    gather1_kernel<<<N_NODES / 4, 256, 0, stream>>>(g1b, row_ptr, csr_src, dinv, b1, hh, hl);

    // ---- 7. layer 2 GEMM: g2b = bf16(dinv*(h@W2)), 32x64 blocks, 512 blocks ----
    {
        dim3 grid(O_DIM / 64, N_NODES / 32);   // MW=1, NW=2
        gemm_mfma_kernel<O_DIM, H_DIM, 1, 2><<<grid, 256, 0, stream>>>(
            hh, hl, w2th, w2tl, dinv, g2b);
    }

    // ---- 8. fused gather 2 + head ----
    gather_head_kernel<<<N_NODES, 128, 0, stream>>>(
        g2b, row_ptr, csr_src, dinv, b2, Wmu, bmu, Wlv, blv, eps,
        mu_out, lv_out, zrh, zrl);

    // ---- 9. adjacency reconstruction ----
    {
        dim3 grid(N_NODES / 128, N_NODES / 128);
        adj_mfma_kernel<<<grid, 256, 0, stream>>>(zrh, zrl, out);
    }
}